// Round 30
// baseline (277.749 us; speedup 1.0000x reference)
//
#include <hip/hip_runtime.h>
#include <math.h>

#define NN 50000
#define EE 800000
#define INC 128
#define HIDC 64
#define OUTC 64
#define LLAYERS 8
#define TOT (EE + NN)
#define NB 196            // col buckets of 256 cols (196*256 = 50176 >= NN)
#define ABLK 256          // phase-A blocks: 1/CU
#define CHUNKA ((TOT + ABLK - 1) / ABLK)

#define WAVE_LDS_FENCE() asm volatile("s_waitcnt lgkmcnt(0)" ::: "memory")

typedef __attribute__((ext_vector_type(8))) short bf16x8;
typedef __attribute__((ext_vector_type(4))) float f32x4;

// bf16 <-> f32 (RTN-even pack; values are finite)
__device__ __forceinline__ float bf2f(unsigned short u) {
    return __uint_as_float(((unsigned int)u) << 16);
}
__device__ __forceinline__ unsigned short f2bf(float f) {
    unsigned int u = __float_as_uint(f);
    u += 0x7FFFu + ((u >> 16) & 1u);
    return (unsigned short)(u >> 16);
}

// ---------------------------------------------------------------------------
// Stage 0: int64-vs-int32 detect, sampled.
__global__ void detect_kernel(const long long* __restrict__ p, int* __restrict__ flag) {
    long long v = p[threadIdx.x];
    if (v < 0 || v >= NN) atomicOr(flag, 1);   // flag=1 -> int32 layout
}

__device__ __forceinline__ int load_row(const void* ei, int is64, int e) {
    return is64 ? (int)((const long long*)ei)[e] : ((const int*)ei)[e];
}
__device__ __forceinline__ int load_col(const void* ei, int is64, int e) {
    return is64 ? (int)((const long long*)ei)[EE + e] : ((const int*)ei)[EE + e];
}

// ---------------------------------------------------------------------------
// CSR build, phase A0: per-bucket edge counts.
__global__ __launch_bounds__(256) void histA(const void* __restrict__ ei,
                                             const int* __restrict__ flag,
                                             int* __restrict__ bcnt) {
    __shared__ int h[NB];
    int tid = threadIdx.x;
    for (int i = tid; i < NB; i += 256) h[i] = 0;
    __syncthreads();
    int is64 = (*flag == 0);
    int lo = blockIdx.x * CHUNKA, hi = lo + CHUNKA; if (hi > TOT) hi = TOT;
    for (int e = lo + tid; e < hi; e += 256) {
        int c = (e < EE) ? load_col(ei, is64, e) : (e - EE);
        atomicAdd(&h[c >> 8], 1);
    }
    __syncthreads();
    for (int i = tid; i < NB; i += 256) if (h[i]) atomicAdd(&bcnt[i], h[i]);
}

// phase A1: exclusive scan of bucket counts -> bstart[NB+1], bcur init.
__global__ __launch_bounds__(256) void scan_buckets(const int* __restrict__ bcnt,
                                                    int* __restrict__ bstart,
                                                    int* __restrict__ bcur) {
    __shared__ int s[256];
    int t = threadIdx.x;
    int v = (t < NB) ? bcnt[t] : 0;
    s[t] = v;
    __syncthreads();
    for (int off = 1; off < 256; off <<= 1) {
        int a = (t >= off) ? s[t - off] : 0;
        __syncthreads();
        s[t] += a;
        __syncthreads();
    }
    if (t < NB) { int st = s[t] - v; bstart[t] = st; bcur[t] = st; }
    if (t == NB - 1) bstart[NB] = s[t];
}

// phase A2: scatter PACKED (src<<8 | col&255) into bucket-major barr.
__global__ __launch_bounds__(256) void bucket_scatter(const void* __restrict__ ei,
                                                      const int* __restrict__ flag,
                                                      int* __restrict__ bcur,
                                                      unsigned int* __restrict__ barr) {
    __shared__ int h[NB];
    __shared__ int base[NB];
    int tid = threadIdx.x;
    for (int i = tid; i < NB; i += 256) h[i] = 0;
    __syncthreads();
    int is64 = (*flag == 0);
    int lo = blockIdx.x * CHUNKA, hi = lo + CHUNKA; if (hi > TOT) hi = TOT;
    for (int e = lo + tid; e < hi; e += 256) {
        int c = (e < EE) ? load_col(ei, is64, e) : (e - EE);
        atomicAdd(&h[c >> 8], 1);
    }
    __syncthreads();
    for (int i = tid; i < NB; i += 256) {
        int cnt = h[i];
        base[i] = cnt ? atomicAdd(&bcur[i], cnt) : 0;
        h[i] = 0;                                   // reuse as local cursor
    }
    __syncthreads();
    for (int e = lo + tid; e < hi; e += 256) {
        int r, c;
        if (e < EE) { r = load_row(ei, is64, e); c = load_col(ei, is64, e); }
        else        { r = e - EE; c = r; }
        int b = c >> 8;
        int p = base[b] + atomicAdd(&h[b], 1);
        barr[p] = ((unsigned int)r << 8) | (unsigned int)(c & 255);
    }
}

// phase B0: per-bucket count + in-block scan -> GLOBAL CSR offsets + dinv.
__global__ __launch_bounds__(256) void bucket_offsets(const unsigned int* __restrict__ barr,
                                                      const int* __restrict__ bstart,
                                                      int* __restrict__ offsets,
                                                      float* __restrict__ dinv) {
    __shared__ int cnt[256];
    __shared__ int pre[256];
    int b = blockIdx.x, t = threadIdx.x;
    cnt[t] = 0;
    __syncthreads();
    int lo = bstart[b], hi = bstart[b + 1];
    for (int i = lo + t; i < hi; i += 256) atomicAdd(&cnt[barr[i] & 255u], 1);
    __syncthreads();
    int v = cnt[t];
    pre[t] = v;
    __syncthreads();
    for (int off = 1; off < 256; off <<= 1) {
        int a = (t >= off) ? pre[t - off] : 0;
        __syncthreads();
        pre[t] += a;
        __syncthreads();
    }
    int c = (b << 8) + t;
    if (c <= NN) offsets[c] = bstart[b] + pre[t] - v;   // exclusive prefix
    if (c < NN)  dinv[c] = 1.0f / sqrtf((float)v);      // deg >= 1 (self-loop)
}

// phase B1: place into adj via LDS cursors (init from offsets).
__global__ __launch_bounds__(256) void bucket_place(const unsigned int* __restrict__ barr,
                                                    const int* __restrict__ bstart,
                                                    const int* __restrict__ offsets,
                                                    const float* __restrict__ dinv,
                                                    int2* __restrict__ adj) {
    __shared__ int cur[256];
    int b = blockIdx.x, t = threadIdx.x;
    int c0 = b << 8;
    int c = c0 + t;
    cur[t] = (c < NN) ? offsets[c] : 0;
    __syncthreads();
    int lo = bstart[b], hi = bstart[b + 1];
    for (int i = lo + t; i < hi; i += 256) {
        unsigned int v = barr[i];
        int r = (int)(v >> 8);
        int ci = (int)(v & 255u);
        int pos = atomicAdd(&cur[ci], 1);
        adj[pos] = make_int2(r, __float_as_int(dinv[r] * dinv[c0 + ci]));
    }
}

// ---------------------------------------------------------------------------
// wt_prep: fold all 8 layers' Wt[n][k] = beta_l*W_l[n][k] + (1-beta_l)*d(k,n)
// into bf16 ONCE (64KB total).
__global__ __launch_bounds__(256) void wt_prep(const float* __restrict__ conv_w,
                                               unsigned short* __restrict__ wtg) {
    int idx = blockIdx.x * 256 + threadIdx.x;       // 8*4096 total
    if (idx >= LLAYERS * HIDC * HIDC) return;
    int l = idx >> 12, i = idx & 4095;
    int n = i >> 6, k = i & 63;
    float beta = logf(0.5f / (float)(l + 1) + 1.0f);
    float t = beta * conv_w[idx] + ((k == n) ? (1.0f - beta) : 0.0f);
    wtg[idx] = f2bf(t);
}

// ---------------------------------------------------------------------------
// Stage 4 (MFMA): h(bf16) = relu(x @ w_in^T + b_in); x0b(bf16) = same value.
__global__ __launch_bounds__(256) void in_gemm(const float* __restrict__ x,
                                               const float* __restrict__ w_in,
                                               const float* __restrict__ b_in,
                                               unsigned short* __restrict__ h,
                                               unsigned short* __restrict__ x0b) {
    __shared__ unsigned short xT[16 * 136];
    int tid = threadIdx.x, w = tid >> 6, lane = tid & 63;
    int g = lane >> 4, c = lane & 15;
    int base = blockIdx.x << 4;

    // B fragments: B[k][n] = w_in[n][k], n = w*16+c, k = kt*32 + g*8 + i
    bf16x8 bfrag[4];
    {
        const float* Wrow = w_in + (size_t)((w << 4) + c) * INC;
        #pragma unroll
        for (int kt = 0; kt < 4; ++kt) {
            int k0 = kt * 32 + (g << 3);
            float4 va = *reinterpret_cast<const float4*>(Wrow + k0);
            float4 vb = *reinterpret_cast<const float4*>(Wrow + k0 + 4);
            bf16x8 r;
            r[0] = (short)f2bf(va.x); r[1] = (short)f2bf(va.y);
            r[2] = (short)f2bf(va.z); r[3] = (short)f2bf(va.w);
            r[4] = (short)f2bf(vb.x); r[5] = (short)f2bf(vb.y);
            r[6] = (short)f2bf(vb.z); r[7] = (short)f2bf(vb.w);
            bfrag[kt] = r;
        }
    }

    // Stage x tile: 16 rows x 32 float4 = 512 loads; 2 per thread (coalesced).
    #pragma unroll
    for (int m = 0; m < 2; ++m) {
        int idx = tid * 2 + m;                 // 0..511
        int row = idx >> 5, col4 = idx & 31;
        float4 v = *reinterpret_cast<const float4*>(
            x + (((size_t)(base + row)) << 7) + (col4 << 2));
        ushort4 pk;
        pk.x = f2bf(v.x); pk.y = f2bf(v.y); pk.z = f2bf(v.z); pk.w = f2bf(v.w);
        *reinterpret_cast<ushort4*>(&xT[row * 136 + (col4 << 2)]) = pk;
    }
    __syncthreads();

    // A fragments: A[m][k], m = lane&15, k = kt*32 + (lane>>4)*8 + i
    f32x4 d = {0.f, 0.f, 0.f, 0.f};
    #pragma unroll
    for (int kt = 0; kt < 4; ++kt) {
        bf16x8 a = *reinterpret_cast<const bf16x8*>(&xT[c * 136 + kt * 32 + (g << 3)]);
        d = __builtin_amdgcn_mfma_f32_16x16x32_bf16(a, bfrag[kt], d, 0, 0, 0);
    }
    float bj = b_in[(w << 4) + c];
    #pragma unroll
    for (int r = 0; r < 4; ++r) {
        int node = base + (g << 2) + r;
        int ch = (w << 4) + c;
        unsigned short hv = f2bf(fmaxf(d[r] + bj, 0.0f));
        h[((size_t)node << 6) + ch]   = hv;
        x0b[((size_t)node << 6) + ch] = hv;
    }
}

// ---------------------------------------------------------------------------
// Stage 5: GCNII layer via MFMA, wave-autonomous, TWO interleaved gather
// streams per 16-lane group (nodes nA, nB): doubles independent loads in
// flight per wave (R24's deeper-within-one-node batching failed; this is
// across-node MLP). Wave owns 8 nodes; aggT rows 0-7 valid; store g<2.
#define GATH4(ACC, EPTR) do { \
    int2 a0 = adj[EPTR], a1 = adj[(EPTR) + 1], a2 = adj[(EPTR) + 2], a3 = adj[(EPTR) + 3]; \
    ushort4 h0 = *reinterpret_cast<const ushort4*>(h_in + ((a0.x << 6) + (c << 2))); \
    ushort4 h1 = *reinterpret_cast<const ushort4*>(h_in + ((a1.x << 6) + (c << 2))); \
    ushort4 h2 = *reinterpret_cast<const ushort4*>(h_in + ((a2.x << 6) + (c << 2))); \
    ushort4 h3 = *reinterpret_cast<const ushort4*>(h_in + ((a3.x << 6) + (c << 2))); \
    float n0 = __int_as_float(a0.y), n1 = __int_as_float(a1.y); \
    float n2 = __int_as_float(a2.y), n3 = __int_as_float(a3.y); \
    ACC.x = fmaf(n0, bf2f(h0.x), ACC.x); ACC.y = fmaf(n0, bf2f(h0.y), ACC.y); \
    ACC.z = fmaf(n0, bf2f(h0.z), ACC.z); ACC.w = fmaf(n0, bf2f(h0.w), ACC.w); \
    ACC.x = fmaf(n1, bf2f(h1.x), ACC.x); ACC.y = fmaf(n1, bf2f(h1.y), ACC.y); \
    ACC.z = fmaf(n1, bf2f(h1.z), ACC.z); ACC.w = fmaf(n1, bf2f(h1.w), ACC.w); \
    ACC.x = fmaf(n2, bf2f(h2.x), ACC.x); ACC.y = fmaf(n2, bf2f(h2.y), ACC.y); \
    ACC.z = fmaf(n2, bf2f(h2.z), ACC.z); ACC.w = fmaf(n2, bf2f(h2.w), ACC.w); \
    ACC.x = fmaf(n3, bf2f(h3.x), ACC.x); ACC.y = fmaf(n3, bf2f(h3.y), ACC.y); \
    ACC.z = fmaf(n3, bf2f(h3.z), ACC.z); ACC.w = fmaf(n3, bf2f(h3.w), ACC.w); \
} while (0)
#define GATH1(ACC, EPTR) do { \
    int2 a = adj[EPTR]; \
    ushort4 hv = *reinterpret_cast<const ushort4*>(h_in + ((a.x << 6) + (c << 2))); \
    float nrm = __int_as_float(a.y); \
    ACC.x = fmaf(nrm, bf2f(hv.x), ACC.x); \
    ACC.y = fmaf(nrm, bf2f(hv.y), ACC.y); \
    ACC.z = fmaf(nrm, bf2f(hv.z), ACC.z); \
    ACC.w = fmaf(nrm, bf2f(hv.w), ACC.w); \
} while (0)

__global__ __launch_bounds__(256) void layer_mfma(
        const unsigned short* __restrict__ h_in, unsigned short* __restrict__ h_out,
        const unsigned short* __restrict__ x0b,
        const int* __restrict__ offsets, const int2* __restrict__ adj,
        const unsigned short* __restrict__ wt) {
    __shared__ unsigned short WtL[64 * 72];      // Wt[n][k] bf16, 144B rows
    __shared__ unsigned short aggT[4][16 * 72];  // per-wave A tiles (rows 0-7 used)
    int tid = threadIdx.x, w = tid >> 6, lane = tid & 63;
    int g = lane >> 4, c = lane & 15;

    // Stage Wt (bf16, 1024 ushort4): 4 per thread, coalesced; one pre-gather barrier.
    {
        const ushort4* src = reinterpret_cast<const ushort4*>(wt);
        #pragma unroll
        for (int m = 0; m < 4; ++m) {
            int idx = tid + m * 256;               // 0..1023
            int row = idx >> 4, col4 = idx & 15;
            *reinterpret_cast<ushort4*>(&WtL[row * 72 + (col4 << 2)]) = src[idx];
        }
    }
    __syncthreads();

    // Two nodes per group: nA = row g, nB = row g+4 of this wave's 8-node tile.
    int baseW = blockIdx.x * 32 + w * 8;
    int nA = baseW + g, nB = baseW + 4 + g;
    bool vA = nA < NN, vB = nB < NN;
    int eA = 0, eA1 = 0, eB = 0, eB1 = 0;
    if (vA) { eA = offsets[nA]; eA1 = offsets[nA + 1]; }
    if (vB) { eB = offsets[nB]; eB1 = offsets[nB + 1]; }
    ushort4 xvA = make_ushort4(0, 0, 0, 0), xvB = make_ushort4(0, 0, 0, 0);
    if (vA) xvA = *reinterpret_cast<const ushort4*>(x0b + ((nA << 6) + (c << 2)));
    if (vB) xvB = *reinterpret_cast<const ushort4*>(x0b + ((nB << 6) + (c << 2)));

    float4 accA = make_float4(0.f, 0.f, 0.f, 0.f);
    float4 accB = make_float4(0.f, 0.f, 0.f, 0.f);
    while ((eA + 4 <= eA1) || (eB + 4 <= eB1)) {
        if (eA + 4 <= eA1) { GATH4(accA, eA); eA += 4; }
        if (eB + 4 <= eB1) { GATH4(accB, eB); eB += 4; }
    }
    for (; eA < eA1; ++eA) GATH1(accA, eA);
    for (; eB < eB1; ++eB) GATH1(accB, eB);

    {
        ushort4 pkA, pkB;
        pkA.x = f2bf(fmaf(0.9f, accA.x, 0.1f * bf2f(xvA.x)));
        pkA.y = f2bf(fmaf(0.9f, accA.y, 0.1f * bf2f(xvA.y)));
        pkA.z = f2bf(fmaf(0.9f, accA.z, 0.1f * bf2f(xvA.z)));
        pkA.w = f2bf(fmaf(0.9f, accA.w, 0.1f * bf2f(xvA.w)));
        pkB.x = f2bf(fmaf(0.9f, accB.x, 0.1f * bf2f(xvB.x)));
        pkB.y = f2bf(fmaf(0.9f, accB.y, 0.1f * bf2f(xvB.y)));
        pkB.z = f2bf(fmaf(0.9f, accB.z, 0.1f * bf2f(xvB.z)));
        pkB.w = f2bf(fmaf(0.9f, accB.w, 0.1f * bf2f(xvB.w)));
        *reinterpret_cast<ushort4*>(&aggT[w][g * 72 + (c << 2)])       = pkA;
        *reinterpret_cast<ushort4*>(&aggT[w][(g + 4) * 72 + (c << 2)]) = pkB;
    }
    WAVE_LDS_FENCE();   // wave-private tile: no block barrier needed

    // A fragments (rows 8..15 garbage -> their D outputs never stored)
    bf16x8 afrag0 = *reinterpret_cast<const bf16x8*>(&aggT[w][c * 72 + (g << 3)]);
    bf16x8 afrag1 = *reinterpret_cast<const bf16x8*>(&aggT[w][c * 72 + 32 + (g << 3)]);

    // 4 n-tiles cover all 64 output channels for this wave's 8 nodes.
    #pragma unroll
    for (int t = 0; t < 4; ++t) {
        bf16x8 b0 = *reinterpret_cast<const bf16x8*>(
            &WtL[((t << 4) + c) * 72 + (g << 3)]);
        bf16x8 b1 = *reinterpret_cast<const bf16x8*>(
            &WtL[((t << 4) + c) * 72 + 32 + (g << 3)]);
        f32x4 d = {0.f, 0.f, 0.f, 0.f};
        d = __builtin_amdgcn_mfma_f32_16x16x32_bf16(afrag0, b0, d, 0, 0, 0);
        d = __builtin_amdgcn_mfma_f32_16x16x32_bf16(afrag1, b1, d, 0, 0, 0);
        // D: col = lane&15, row = (lane>>4)*4 + reg. Rows 0..7 real -> g<2.
        if (g < 2) {
            #pragma unroll
            for (int r = 0; r < 4; ++r) {
                int node = baseW + (g << 2) + r;
                if (node < NN) {
                    int ch = (t << 4) + c;
                    h_out[(node << 6) + ch] = f2bf(fmaxf(d[r], 0.0f));
                }
            }
        }
    }
}

// ---------------------------------------------------------------------------
// Stage 6 (MFMA): out = h @ w_out^T + b_out (fp32 out, no relu).
__global__ __launch_bounds__(256) void out_gemm(const unsigned short* __restrict__ h,
                                                const float* __restrict__ w_out,
                                                const float* __restrict__ b_out,
                                                float* __restrict__ out) {
    __shared__ unsigned short hT[16 * 72];
    int tid = threadIdx.x, w = tid >> 6, lane = tid & 63;
    int g = lane >> 4, c = lane & 15;
    int base = blockIdx.x << 4;

    // B fragments: B[k][n] = w_out[n][k], n = w*16+c, k = kt*32 + g*8 + i
    bf16x8 bfrag[2];
    {
        const float* Wrow = w_out + (size_t)((w << 4) + c) * HIDC;
        #pragma unroll
        for (int kt = 0; kt < 2; ++kt) {
            int k0 = kt * 32 + (g << 3);
            float4 va = *reinterpret_cast<const float4*>(Wrow + k0);
            float4 vb = *reinterpret_cast<const float4*>(Wrow + k0 + 4);
            bf16x8 r;
            r[0] = (short)f2bf(va.x); r[1] = (short)f2bf(va.y);
            r[2] = (short)f2bf(va.z); r[3] = (short)f2bf(va.w);
            r[4] = (short)f2bf(vb.x); r[5] = (short)f2bf(vb.y);
            r[6] = (short)f2bf(vb.z); r[7] = (short)f2bf(vb.w);
            bfrag[kt] = r;
        }
    }

    // Stage h tile: 16 rows x 16 ushort4 = 256 loads; 1 per thread.
    {
        int row = tid >> 4, col4 = tid & 15;
        ushort4 v = *reinterpret_cast<const ushort4*>(
            h + ((size_t)(base + row) << 6) + (col4 << 2));
        *reinterpret_cast<ushort4*>(&hT[row * 72 + (col4 << 2)]) = v;
    }
    __syncthreads();

    bf16x8 a0 = *reinterpret_cast<const bf16x8*>(&hT[c * 72 + (g << 3)]);
    bf16x8 a1 = *reinterpret_cast<const bf16x8*>(&hT[c * 72 + 32 + (g << 3)]);
    f32x4 d = {0.f, 0.f, 0.f, 0.f};
    d = __builtin_amdgcn_mfma_f32_16x16x32_bf16(a0, bfrag[0], d, 0, 0, 0);
    d = __builtin_amdgcn_mfma_f32_16x16x32_bf16(a1, bfrag[1], d, 0, 0, 0);

    float bj = b_out[(w << 4) + c];
    #pragma unroll
    for (int r = 0; r < 4; ++r) {
        int node = base + (g << 2) + r;
        int ch = (w << 4) + c;
        out[((size_t)node << 6) + ch] = d[r] + bj;
    }
}

extern "C" void kernel_launch(void* const* d_in, const int* in_sizes, int n_in,
                              void* d_out, int out_size, void* d_ws, size_t ws_size,
                              hipStream_t stream) {
    const float* x      = (const float*)d_in[0];
    const void*  ei     = d_in[1];
    const float* w_in   = (const float*)d_in[2];
    const float* b_in   = (const float*)d_in[3];
    const float* conv_w = (const float*)d_in[4];
    const float* w_out  = (const float*)d_in[5];
    const float* b_out  = (const float*)d_in[6];
    float* out = (float*)d_out;

    char* ws = (char*)d_ws;
    size_t off = 0;
    auto alloc = [&](size_t bytes) -> void* {
        void* p = ws + off;
        off += (bytes + 255) & ~(size_t)255;
        return p;
    };
    int*   flag    = (int*)alloc(4);
    float* dinv    = (float*)alloc((size_t)NN * 4);
    int*   offsets = (int*)alloc((size_t)(NN + 1) * 4);
    int*   bcnt    = (int*)alloc((size_t)NB * 4);
    int*   bstart  = (int*)alloc((size_t)(NB + 1) * 4);
    int*   bcur    = (int*)alloc((size_t)NB * 4);
    unsigned short* wtg = (unsigned short*)alloc((size_t)LLAYERS * HIDC * HIDC * 2);
    int2*  adj     = (int2*)alloc((size_t)TOT * 8);
    unsigned short* hA  = (unsigned short*)alloc((size_t)NN * HIDC * 2);
    unsigned short* hB  = (unsigned short*)alloc((size_t)NN * HIDC * 2);
    unsigned short* x0b = (unsigned short*)alloc((size_t)NN * HIDC * 2);
    // barr (3.4 MB packed) aliases hA (6.4 MB): consumed by bucket_place
    // before in_gemm writes hA.
    unsigned int* barr = (unsigned int*)hA;

    hipMemsetAsync(flag, 0, 4, stream);
    hipMemsetAsync(bcnt, 0, (size_t)NB * 4, stream);
    detect_kernel<<<1, 256, 0, stream>>>((const long long*)ei, flag);
    histA<<<ABLK, 256, 0, stream>>>(ei, flag, bcnt);
    scan_buckets<<<1, 256, 0, stream>>>(bcnt, bstart, bcur);
    bucket_scatter<<<ABLK, 256, 0, stream>>>(ei, flag, bcur, barr);
    bucket_offsets<<<NB, 256, 0, stream>>>(barr, bstart, offsets, dinv);
    bucket_place<<<NB, 256, 0, stream>>>(barr, bstart, offsets, dinv, adj);
    wt_prep<<<(LLAYERS * HIDC * HIDC + 255) / 256, 256, 0, stream>>>(conv_w, wtg);
    in_gemm<<<NN / 16, 256, 0, stream>>>(x, w_in, b_in, hA, x0b);

    unsigned short* cur = hA;
    unsigned short* nxt = hB;
    for (int l = 0; l < LLAYERS; ++l) {
        const unsigned short* wtl = wtg + (size_t)l * HIDC * HIDC;
        layer_mfma<<<(NN + 31) / 32, 256, 0, stream>>>(cur, nxt, x0b, offsets, adj, wtl);
        unsigned short* t = cur; cur = nxt; nxt = t;
    }
    out_gemm<<<NN / 16, 256, 0, stream>>>(cur, w_out, b_out, out);
}

// Round 31
// 267.756 us; speedup vs baseline: 1.0373x; 1.0373x over previous
//
#include <hip/hip_runtime.h>
#include <math.h>

#define NN 50000
#define EE 800000
#define INC 128
#define HIDC 64
#define OUTC 64
#define LLAYERS 8
#define TOT (EE + NN)
#define NB 196            // col buckets of 256 cols (196*256 = 50176 >= NN)
#define ABLK 256          // phase-A blocks: 1/CU
#define CHUNKA ((TOT + ABLK - 1) / ABLK)

#define WAVE_LDS_FENCE() asm volatile("s_waitcnt lgkmcnt(0)" ::: "memory")

typedef __attribute__((ext_vector_type(8))) short bf16x8;
typedef __attribute__((ext_vector_type(4))) float f32x4;

// bf16 <-> f32 (RTN-even pack; values are finite)
__device__ __forceinline__ float bf2f(unsigned short u) {
    return __uint_as_float(((unsigned int)u) << 16);
}
__device__ __forceinline__ unsigned short f2bf(float f) {
    unsigned int u = __float_as_uint(f);
    u += 0x7FFFu + ((u >> 16) & 1u);
    return (unsigned short)(u >> 16);
}

// ---------------------------------------------------------------------------
// Stage 0: int64-vs-int32 detect, sampled.
__global__ void detect_kernel(const long long* __restrict__ p, int* __restrict__ flag) {
    long long v = p[threadIdx.x];
    if (v < 0 || v >= NN) atomicOr(flag, 1);   // flag=1 -> int32 layout
}

__device__ __forceinline__ int load_row(const void* ei, int is64, int e) {
    return is64 ? (int)((const long long*)ei)[e] : ((const int*)ei)[e];
}
__device__ __forceinline__ int load_col(const void* ei, int is64, int e) {
    return is64 ? (int)((const long long*)ei)[EE + e] : ((const int*)ei)[EE + e];
}

// ---------------------------------------------------------------------------
// CSR build, phase A0: per-bucket edge counts.
__global__ __launch_bounds__(256) void histA(const void* __restrict__ ei,
                                             const int* __restrict__ flag,
                                             int* __restrict__ bcnt) {
    __shared__ int h[NB];
    int tid = threadIdx.x;
    for (int i = tid; i < NB; i += 256) h[i] = 0;
    __syncthreads();
    int is64 = (*flag == 0);
    int lo = blockIdx.x * CHUNKA, hi = lo + CHUNKA; if (hi > TOT) hi = TOT;
    for (int e = lo + tid; e < hi; e += 256) {
        int c = (e < EE) ? load_col(ei, is64, e) : (e - EE);
        atomicAdd(&h[c >> 8], 1);
    }
    __syncthreads();
    for (int i = tid; i < NB; i += 256) if (h[i]) atomicAdd(&bcnt[i], h[i]);
}

// phase A1: exclusive scan of bucket counts -> bstart[NB+1], bcur init.
__global__ __launch_bounds__(256) void scan_buckets(const int* __restrict__ bcnt,
                                                    int* __restrict__ bstart,
                                                    int* __restrict__ bcur) {
    __shared__ int s[256];
    int t = threadIdx.x;
    int v = (t < NB) ? bcnt[t] : 0;
    s[t] = v;
    __syncthreads();
    for (int off = 1; off < 256; off <<= 1) {
        int a = (t >= off) ? s[t - off] : 0;
        __syncthreads();
        s[t] += a;
        __syncthreads();
    }
    if (t < NB) { int st = s[t] - v; bstart[t] = st; bcur[t] = st; }
    if (t == NB - 1) bstart[NB] = s[t];
}

// phase A2: scatter PACKED (src<<8 | col&255) into bucket-major barr.
__global__ __launch_bounds__(256) void bucket_scatter(const void* __restrict__ ei,
                                                      const int* __restrict__ flag,
                                                      int* __restrict__ bcur,
                                                      unsigned int* __restrict__ barr) {
    __shared__ int h[NB];
    __shared__ int base[NB];
    int tid = threadIdx.x;
    for (int i = tid; i < NB; i += 256) h[i] = 0;
    __syncthreads();
    int is64 = (*flag == 0);
    int lo = blockIdx.x * CHUNKA, hi = lo + CHUNKA; if (hi > TOT) hi = TOT;
    for (int e = lo + tid; e < hi; e += 256) {
        int c = (e < EE) ? load_col(ei, is64, e) : (e - EE);
        atomicAdd(&h[c >> 8], 1);
    }
    __syncthreads();
    for (int i = tid; i < NB; i += 256) {
        int cnt = h[i];
        base[i] = cnt ? atomicAdd(&bcur[i], cnt) : 0;
        h[i] = 0;                                   // reuse as local cursor
    }
    __syncthreads();
    for (int e = lo + tid; e < hi; e += 256) {
        int r, c;
        if (e < EE) { r = load_row(ei, is64, e); c = load_col(ei, is64, e); }
        else        { r = e - EE; c = r; }
        int b = c >> 8;
        int p = base[b] + atomicAdd(&h[b], 1);
        barr[p] = ((unsigned int)r << 8) | (unsigned int)(c & 255);
    }
}

// phase B0: per-bucket count + in-block scan -> GLOBAL CSR offsets + dinv.
__global__ __launch_bounds__(256) void bucket_offsets(const unsigned int* __restrict__ barr,
                                                      const int* __restrict__ bstart,
                                                      int* __restrict__ offsets,
                                                      float* __restrict__ dinv) {
    __shared__ int cnt[256];
    __shared__ int pre[256];
    int b = blockIdx.x, t = threadIdx.x;
    cnt[t] = 0;
    __syncthreads();
    int lo = bstart[b], hi = bstart[b + 1];
    for (int i = lo + t; i < hi; i += 256) atomicAdd(&cnt[barr[i] & 255u], 1);
    __syncthreads();
    int v = cnt[t];
    pre[t] = v;
    __syncthreads();
    for (int off = 1; off < 256; off <<= 1) {
        int a = (t >= off) ? pre[t - off] : 0;
        __syncthreads();
        pre[t] += a;
        __syncthreads();
    }
    int c = (b << 8) + t;
    if (c <= NN) offsets[c] = bstart[b] + pre[t] - v;   // exclusive prefix
    if (c < NN)  dinv[c] = 1.0f / sqrtf((float)v);      // deg >= 1 (self-loop)
}

// phase B1: place into adj via LDS cursors (init from offsets).
__global__ __launch_bounds__(256) void bucket_place(const unsigned int* __restrict__ barr,
                                                    const int* __restrict__ bstart,
                                                    const int* __restrict__ offsets,
                                                    const float* __restrict__ dinv,
                                                    int2* __restrict__ adj) {
    __shared__ int cur[256];
    int b = blockIdx.x, t = threadIdx.x;
    int c0 = b << 8;
    int c = c0 + t;
    cur[t] = (c < NN) ? offsets[c] : 0;
    __syncthreads();
    int lo = bstart[b], hi = bstart[b + 1];
    for (int i = lo + t; i < hi; i += 256) {
        unsigned int v = barr[i];
        int r = (int)(v >> 8);
        int ci = (int)(v & 255u);
        int pos = atomicAdd(&cur[ci], 1);
        adj[pos] = make_int2(r, __float_as_int(dinv[r] * dinv[c0 + ci]));
    }
}

// ---------------------------------------------------------------------------
// wt_prep: fold all 8 layers' Wt[n][k] = beta_l*W_l[n][k] + (1-beta_l)*d(k,n)
// into bf16 ONCE (64KB total).
__global__ __launch_bounds__(256) void wt_prep(const float* __restrict__ conv_w,
                                               unsigned short* __restrict__ wtg) {
    int idx = blockIdx.x * 256 + threadIdx.x;       // 8*4096 total
    if (idx >= LLAYERS * HIDC * HIDC) return;
    int l = idx >> 12, i = idx & 4095;
    int n = i >> 6, k = i & 63;
    float beta = logf(0.5f / (float)(l + 1) + 1.0f);
    float t = beta * conv_w[idx] + ((k == n) ? (1.0f - beta) : 0.0f);
    wtg[idx] = f2bf(t);
}

// ---------------------------------------------------------------------------
// Stage 4 (MFMA): h(bf16) = relu(x @ w_in^T + b_in); x0b(bf16) = same value.
__global__ __launch_bounds__(256) void in_gemm(const float* __restrict__ x,
                                               const float* __restrict__ w_in,
                                               const float* __restrict__ b_in,
                                               unsigned short* __restrict__ h,
                                               unsigned short* __restrict__ x0b) {
    __shared__ unsigned short xT[16 * 136];
    int tid = threadIdx.x, w = tid >> 6, lane = tid & 63;
    int g = lane >> 4, c = lane & 15;
    int base = blockIdx.x << 4;

    // B fragments: B[k][n] = w_in[n][k], n = w*16+c, k = kt*32 + g*8 + i
    bf16x8 bfrag[4];
    {
        const float* Wrow = w_in + (size_t)((w << 4) + c) * INC;
        #pragma unroll
        for (int kt = 0; kt < 4; ++kt) {
            int k0 = kt * 32 + (g << 3);
            float4 va = *reinterpret_cast<const float4*>(Wrow + k0);
            float4 vb = *reinterpret_cast<const float4*>(Wrow + k0 + 4);
            bf16x8 r;
            r[0] = (short)f2bf(va.x); r[1] = (short)f2bf(va.y);
            r[2] = (short)f2bf(va.z); r[3] = (short)f2bf(va.w);
            r[4] = (short)f2bf(vb.x); r[5] = (short)f2bf(vb.y);
            r[6] = (short)f2bf(vb.z); r[7] = (short)f2bf(vb.w);
            bfrag[kt] = r;
        }
    }

    // Stage x tile: 16 rows x 32 float4 = 512 loads; 2 per thread (coalesced).
    #pragma unroll
    for (int m = 0; m < 2; ++m) {
        int idx = tid * 2 + m;                 // 0..511
        int row = idx >> 5, col4 = idx & 31;
        float4 v = *reinterpret_cast<const float4*>(
            x + (((size_t)(base + row)) << 7) + (col4 << 2));
        ushort4 pk;
        pk.x = f2bf(v.x); pk.y = f2bf(v.y); pk.z = f2bf(v.z); pk.w = f2bf(v.w);
        *reinterpret_cast<ushort4*>(&xT[row * 136 + (col4 << 2)]) = pk;
    }
    __syncthreads();

    // A fragments: A[m][k], m = lane&15, k = kt*32 + (lane>>4)*8 + i
    f32x4 d = {0.f, 0.f, 0.f, 0.f};
    #pragma unroll
    for (int kt = 0; kt < 4; ++kt) {
        bf16x8 a = *reinterpret_cast<const bf16x8*>(&xT[c * 136 + kt * 32 + (g << 3)]);
        d = __builtin_amdgcn_mfma_f32_16x16x32_bf16(a, bfrag[kt], d, 0, 0, 0);
    }
    float bj = b_in[(w << 4) + c];
    #pragma unroll
    for (int r = 0; r < 4; ++r) {
        int node = base + (g << 2) + r;
        int ch = (w << 4) + c;
        unsigned short hv = f2bf(fmaxf(d[r] + bj, 0.0f));
        h[((size_t)node << 6) + ch]   = hv;
        x0b[((size_t)node << 6) + ch] = hv;
    }
}

// ---------------------------------------------------------------------------
// Stage 5: GCNII layer via MFMA, wave-autonomous (R29-proven best, 269.4us).
// 4 nodes/wave, 3125 blocks (TLP is the latency hider: R30's 1563-block
// dual-stream variant regressed). Wt staged bf16 global->LDS per block;
// one pre-gather barrier; bf16 x0 residual.
__global__ __launch_bounds__(256) void layer_mfma(
        const unsigned short* __restrict__ h_in, unsigned short* __restrict__ h_out,
        const unsigned short* __restrict__ x0b,
        const int* __restrict__ offsets, const int2* __restrict__ adj,
        const unsigned short* __restrict__ wt) {
    __shared__ unsigned short WtL[64 * 72];      // Wt[n][k] bf16, 144B rows
    __shared__ unsigned short aggT[4][16 * 72];  // per-wave A tiles (rows 4-15 unused)
    int tid = threadIdx.x, w = tid >> 6, lane = tid & 63;
    int g = lane >> 4, c = lane & 15;

    // Stage Wt (bf16, 4096 ushorts = 1024 ushort4): 4 per thread, coalesced.
    {
        const ushort4* src = reinterpret_cast<const ushort4*>(wt);
        #pragma unroll
        for (int m = 0; m < 4; ++m) {
            int idx = tid + m * 256;               // 0..1023
            int row = idx >> 4, col4 = idx & 15;
            *reinterpret_cast<ushort4*>(&WtL[row * 72 + (col4 << 2)]) = src[idx];
        }
    }
    __syncthreads();

    // Gather: group g of wave w handles node base + w*4 + g (wave-local).
    int base = blockIdx.x << 4;
    int n = base + (w << 2) + g;
    int e0 = offsets[n], e1 = offsets[n + 1];
    // Issue the residual read early: no dependence on the gather loop.
    ushort4 xv = *reinterpret_cast<const ushort4*>(x0b + ((n << 6) + (c << 2)));
    float4 acc = make_float4(0.f, 0.f, 0.f, 0.f);
    int e = e0;
    for (; e + 4 <= e1; e += 4) {
        int2 a0 = adj[e], a1 = adj[e + 1], a2 = adj[e + 2], a3 = adj[e + 3];
        ushort4 h0 = *reinterpret_cast<const ushort4*>(h_in + ((a0.x << 6) + (c << 2)));
        ushort4 h1 = *reinterpret_cast<const ushort4*>(h_in + ((a1.x << 6) + (c << 2)));
        ushort4 h2 = *reinterpret_cast<const ushort4*>(h_in + ((a2.x << 6) + (c << 2)));
        ushort4 h3 = *reinterpret_cast<const ushort4*>(h_in + ((a3.x << 6) + (c << 2)));
        float n0 = __int_as_float(a0.y), n1 = __int_as_float(a1.y);
        float n2 = __int_as_float(a2.y), n3 = __int_as_float(a3.y);
        acc.x = fmaf(n0, bf2f(h0.x), acc.x); acc.y = fmaf(n0, bf2f(h0.y), acc.y);
        acc.z = fmaf(n0, bf2f(h0.z), acc.z); acc.w = fmaf(n0, bf2f(h0.w), acc.w);
        acc.x = fmaf(n1, bf2f(h1.x), acc.x); acc.y = fmaf(n1, bf2f(h1.y), acc.y);
        acc.z = fmaf(n1, bf2f(h1.z), acc.z); acc.w = fmaf(n1, bf2f(h1.w), acc.w);
        acc.x = fmaf(n2, bf2f(h2.x), acc.x); acc.y = fmaf(n2, bf2f(h2.y), acc.y);
        acc.z = fmaf(n2, bf2f(h2.z), acc.z); acc.w = fmaf(n2, bf2f(h2.w), acc.w);
        acc.x = fmaf(n3, bf2f(h3.x), acc.x); acc.y = fmaf(n3, bf2f(h3.y), acc.y);
        acc.z = fmaf(n3, bf2f(h3.z), acc.z); acc.w = fmaf(n3, bf2f(h3.w), acc.w);
    }
    for (; e < e1; ++e) {
        int2 a = adj[e];
        ushort4 hv = *reinterpret_cast<const ushort4*>(h_in + ((a.x << 6) + (c << 2)));
        float nrm = __int_as_float(a.y);
        acc.x = fmaf(nrm, bf2f(hv.x), acc.x);
        acc.y = fmaf(nrm, bf2f(hv.y), acc.y);
        acc.z = fmaf(nrm, bf2f(hv.z), acc.z);
        acc.w = fmaf(nrm, bf2f(hv.w), acc.w);
    }
    {
        ushort4 pk;
        pk.x = f2bf(fmaf(0.9f, acc.x, 0.1f * bf2f(xv.x)));
        pk.y = f2bf(fmaf(0.9f, acc.y, 0.1f * bf2f(xv.y)));
        pk.z = f2bf(fmaf(0.9f, acc.z, 0.1f * bf2f(xv.z)));
        pk.w = f2bf(fmaf(0.9f, acc.w, 0.1f * bf2f(xv.w)));
        *reinterpret_cast<ushort4*>(&aggT[w][g * 72 + (c << 2)]) = pk;
    }
    WAVE_LDS_FENCE();   // wave-private tile: no block barrier needed

    // A fragments (rows 4..15 garbage -> their D outputs never stored)
    bf16x8 afrag0 = *reinterpret_cast<const bf16x8*>(&aggT[w][c * 72 + (g << 3)]);
    bf16x8 afrag1 = *reinterpret_cast<const bf16x8*>(&aggT[w][c * 72 + 32 + (g << 3)]);

    // 4 n-tiles cover all 64 output channels for this wave's 4 nodes.
    #pragma unroll
    for (int t = 0; t < 4; ++t) {
        bf16x8 b0 = *reinterpret_cast<const bf16x8*>(
            &WtL[((t << 4) + c) * 72 + (g << 3)]);
        bf16x8 b1 = *reinterpret_cast<const bf16x8*>(
            &WtL[((t << 4) + c) * 72 + 32 + (g << 3)]);
        f32x4 d = {0.f, 0.f, 0.f, 0.f};
        d = __builtin_amdgcn_mfma_f32_16x16x32_bf16(afrag0, b0, d, 0, 0, 0);
        d = __builtin_amdgcn_mfma_f32_16x16x32_bf16(afrag1, b1, d, 0, 0, 0);
        if (g == 0) {
            #pragma unroll
            for (int r = 0; r < 4; ++r) {
                int node = base + (w << 2) + r;
                int ch = (t << 4) + c;
                h_out[(node << 6) + ch] = f2bf(fmaxf(d[r], 0.0f));
            }
        }
    }
}

// ---------------------------------------------------------------------------
// Stage 6 (MFMA): out = h @ w_out^T + b_out (fp32 out, no relu).
__global__ __launch_bounds__(256) void out_gemm(const unsigned short* __restrict__ h,
                                                const float* __restrict__ w_out,
                                                const float* __restrict__ b_out,
                                                float* __restrict__ out) {
    __shared__ unsigned short hT[16 * 72];
    int tid = threadIdx.x, w = tid >> 6, lane = tid & 63;
    int g = lane >> 4, c = lane & 15;
    int base = blockIdx.x << 4;

    // B fragments: B[k][n] = w_out[n][k], n = w*16+c, k = kt*32 + g*8 + i
    bf16x8 bfrag[2];
    {
        const float* Wrow = w_out + (size_t)((w << 4) + c) * HIDC;
        #pragma unroll
        for (int kt = 0; kt < 2; ++kt) {
            int k0 = kt * 32 + (g << 3);
            float4 va = *reinterpret_cast<const float4*>(Wrow + k0);
            float4 vb = *reinterpret_cast<const float4*>(Wrow + k0 + 4);
            bf16x8 r;
            r[0] = (short)f2bf(va.x); r[1] = (short)f2bf(va.y);
            r[2] = (short)f2bf(va.z); r[3] = (short)f2bf(va.w);
            r[4] = (short)f2bf(vb.x); r[5] = (short)f2bf(vb.y);
            r[6] = (short)f2bf(vb.z); r[7] = (short)f2bf(vb.w);
            bfrag[kt] = r;
        }
    }

    // Stage h tile: 16 rows x 16 ushort4 = 256 loads; 1 per thread.
    {
        int row = tid >> 4, col4 = tid & 15;
        ushort4 v = *reinterpret_cast<const ushort4*>(
            h + ((size_t)(base + row) << 6) + (col4 << 2));
        *reinterpret_cast<ushort4*>(&hT[row * 72 + (col4 << 2)]) = v;
    }
    __syncthreads();

    bf16x8 a0 = *reinterpret_cast<const bf16x8*>(&hT[c * 72 + (g << 3)]);
    bf16x8 a1 = *reinterpret_cast<const bf16x8*>(&hT[c * 72 + 32 + (g << 3)]);
    f32x4 d = {0.f, 0.f, 0.f, 0.f};
    d = __builtin_amdgcn_mfma_f32_16x16x32_bf16(a0, bfrag[0], d, 0, 0, 0);
    d = __builtin_amdgcn_mfma_f32_16x16x32_bf16(a1, bfrag[1], d, 0, 0, 0);

    float bj = b_out[(w << 4) + c];
    #pragma unroll
    for (int r = 0; r < 4; ++r) {
        int node = base + (g << 2) + r;
        int ch = (w << 4) + c;
        out[((size_t)node << 6) + ch] = d[r] + bj;
    }
}

extern "C" void kernel_launch(void* const* d_in, const int* in_sizes, int n_in,
                              void* d_out, int out_size, void* d_ws, size_t ws_size,
                              hipStream_t stream) {
    const float* x      = (const float*)d_in[0];
    const void*  ei     = d_in[1];
    const float* w_in   = (const float*)d_in[2];
    const float* b_in   = (const float*)d_in[3];
    const float* conv_w = (const float*)d_in[4];
    const float* w_out  = (const float*)d_in[5];
    const float* b_out  = (const float*)d_in[6];
    float* out = (float*)d_out;

    char* ws = (char*)d_ws;
    size_t off = 0;
    auto alloc = [&](size_t bytes) -> void* {
        void* p = ws + off;
        off += (bytes + 255) & ~(size_t)255;
        return p;
    };
    int*   flag    = (int*)alloc(4);
    float* dinv    = (float*)alloc((size_t)NN * 4);
    int*   offsets = (int*)alloc((size_t)(NN + 1) * 4);
    int*   bcnt    = (int*)alloc((size_t)NB * 4);
    int*   bstart  = (int*)alloc((size_t)(NB + 1) * 4);
    int*   bcur    = (int*)alloc((size_t)NB * 4);
    unsigned short* wtg = (unsigned short*)alloc((size_t)LLAYERS * HIDC * HIDC * 2);
    int2*  adj     = (int2*)alloc((size_t)TOT * 8);
    unsigned short* hA  = (unsigned short*)alloc((size_t)NN * HIDC * 2);
    unsigned short* hB  = (unsigned short*)alloc((size_t)NN * HIDC * 2);
    unsigned short* x0b = (unsigned short*)alloc((size_t)NN * HIDC * 2);
    // barr (3.4 MB packed) aliases hA (6.4 MB): consumed by bucket_place
    // before in_gemm writes hA.
    unsigned int* barr = (unsigned int*)hA;

    hipMemsetAsync(flag, 0, 4, stream);
    hipMemsetAsync(bcnt, 0, (size_t)NB * 4, stream);
    detect_kernel<<<1, 256, 0, stream>>>((const long long*)ei, flag);
    histA<<<ABLK, 256, 0, stream>>>(ei, flag, bcnt);
    scan_buckets<<<1, 256, 0, stream>>>(bcnt, bstart, bcur);
    bucket_scatter<<<ABLK, 256, 0, stream>>>(ei, flag, bcur, barr);
    bucket_offsets<<<NB, 256, 0, stream>>>(barr, bstart, offsets, dinv);
    bucket_place<<<NB, 256, 0, stream>>>(barr, bstart, offsets, dinv, adj);
    wt_prep<<<(LLAYERS * HIDC * HIDC + 255) / 256, 256, 0, stream>>>(conv_w, wtg);
    in_gemm<<<NN / 16, 256, 0, stream>>>(x, w_in, b_in, hA, x0b);

    unsigned short* cur = hA;
    unsigned short* nxt = hB;
    for (int l = 0; l < LLAYERS; ++l) {
        const unsigned short* wtl = wtg + (size_t)l * HIDC * HIDC;
        layer_mfma<<<NN / 16, 256, 0, stream>>>(cur, nxt, x0b, offsets, adj, wtl);
        unsigned short* t = cur; cur = nxt; nxt = t;
    }
    out_gemm<<<NN / 16, 256, 0, stream>>>(cur, w_out, b_out, out);
}